// Round 3
// baseline (768.604 us; speedup 1.0000x reference)
//
#include <hip/hip_runtime.h>
#include <math.h>

#define FDIM 64
#define RDIM 16
#define LN2F 0.69314718055994530942f
#define LTS 68     // LDS tile row stride (floats)
#define CPAD 16    // counter padding: one int per 64B line (kills cross-XCD line ping-pong)

typedef __bf16 bf8_t __attribute__((ext_vector_type(8)));
typedef float  f4_t  __attribute__((ext_vector_type(4)));

// Numerically stable softplus (fast intrinsics)
__device__ __forceinline__ float sp(float x) {
    return fmaxf(x, 0.0f) + __logf(1.0f + __expf(-fabsf(x)));
}

// ---------------- weight prep: fp32 [k][c] -> bf16 B-fragment layout ----------
__global__ __launch_bounds__(256) void k_prep(
    const float* s0, const float* s1, const float* s2, const float* s3,
    const float* s4, const float* s5, const float* s6, const float* s7,
    const float* s8, __bf16* __restrict__ dst)
{
    const float* srcs[9] = {s0, s1, s2, s3, s4, s5, s6, s7, s8};
    const float* W = srcs[blockIdx.x];
    __bf16* d = dst + (size_t)blockIdx.x * 4096;
    for (int slot = threadIdx.x; slot < 512; slot += 256) {
        int f = slot >> 6, l = slot & 63;
        int kt = f >> 2, nt = f & 3;
        int row0 = kt * 32 + (l >> 4) * 8;
        int col = nt * 16 + (l & 15);
#pragma unroll
        for (int j = 0; j < 8; ++j)
            d[slot * 8 + j] = (__bf16)W[(row0 + j) * FDIM + col];
    }
}

// ---------------- histogram (padded counters, 4 atomics in flight) ------------
__global__ __launch_bounds__(256) void k_hist(
    const int* __restrict__ idx_i, int* __restrict__ cntP, int P)
{
    int t = blockIdx.x * blockDim.x + threadIdx.x;
    int n = gridDim.x * blockDim.x;
    int p = t;
    for (; p + 3 * n < P; p += 4 * n) {
        int i0 = idx_i[p];
        int i1 = idx_i[p + n];
        int i2 = idx_i[p + 2 * n];
        int i3 = idx_i[p + 3 * n];
        atomicAdd(&cntP[(size_t)i0 * CPAD], 1);
        atomicAdd(&cntP[(size_t)i1 * CPAD], 1);
        atomicAdd(&cntP[(size_t)i2 * CPAD], 1);
        atomicAdd(&cntP[(size_t)i3 * CPAD], 1);
    }
    for (; p < P; p += n) atomicAdd(&cntP[(size_t)idx_i[p] * CPAD], 1);
}

// ---------------- tile in: coalesced global -> wave-private LDS ----------------
__device__ __forceinline__ void tile_in(float* T, const float* __restrict__ src,
                                        int a0, int rows, int lane)
{
#pragma unroll 4
    for (int i = 0; i < 16; ++i) {
        int r = i * 4 + (lane >> 4);
        int col = (lane & 15) * 4;
        float4 val = make_float4(0.f, 0.f, 0.f, 0.f);
        if (r < rows) val = *(const float4*)&src[(size_t)(a0 + r) * FDIM + col];
        *(float4*)&T[r * LTS + col] = val;
    }
}

// build A-fragments (bf16) for a 64x64 LDS tile: aF[mt][kt]
__device__ __forceinline__ void build_a(const float* T, int lane, bool actLn2,
                                        bf8_t (&aF)[4][2])
{
    const int l15 = lane & 15, quad = lane >> 4;
#pragma unroll
    for (int mt = 0; mt < 4; ++mt) {
#pragma unroll
        for (int kt = 0; kt < 2; ++kt) {
            const float* rp = &T[(mt * 16 + l15) * LTS + kt * 32 + quad * 8];
            float4 u0 = *(const float4*)rp;
            float4 u1 = *(const float4*)(rp + 4);
            float e[8] = {u0.x, u0.y, u0.z, u0.w, u1.x, u1.y, u1.z, u1.w};
            bf8_t f;
#pragma unroll
            for (int j = 0; j < 8; ++j) {
                float t = actLn2 ? (sp(e[j]) - LN2F) : e[j];
                f[j] = (__bf16)t;
            }
            aF[mt][kt] = f;
        }
    }
}

// ---------------- k_atoms: x=sp(emb)-ln2; v=sp(x@Wi+bi); y=sp(x@Wj+bj) --------
__global__ __launch_bounds__(256) void k_atoms(
    const float* __restrict__ emb, const __bf16* __restrict__ wf,
    const float* __restrict__ bi, const float* __restrict__ bj,
    float* __restrict__ v, float* __restrict__ y, int N)
{
    __shared__ float tile[4][64 * LTS];
    const int lane = threadIdx.x & 63;
    const int wv = threadIdx.x >> 6;
    float* T = tile[wv];
    const int l15 = lane & 15, quad = lane >> 4;

    const bf8_t* wiF = (const bf8_t*)wf;            // matrix 0
    const bf8_t* wjF = (const bf8_t*)(wf + 4096);   // matrix 1
    bf8_t wi[2][4], wj[2][4];
#pragma unroll
    for (int kt = 0; kt < 2; ++kt)
#pragma unroll
        for (int nt = 0; nt < 4; ++nt) {
            wi[kt][nt] = wiF[(kt * 4 + nt) * 64 + lane];
            wj[kt][nt] = wjF[(kt * 4 + nt) * 64 + lane];
        }
    float biv[4], bjv[4];
#pragma unroll
    for (int nt = 0; nt < 4; ++nt) {
        biv[nt] = bi[nt * 16 + l15];
        bjv[nt] = bj[nt * 16 + l15];
    }

    const int nTiles = (N + 63) >> 6;
    for (int t = blockIdx.x * 4 + wv; t < nTiles; t += gridDim.x * 4) {
        const int a0 = t << 6;
        const int rows = min(64, N - a0);
        tile_in(T, emb, a0, rows, lane);
        bf8_t aF[4][2];
        build_a(T, lane, true, aF);
#pragma unroll
        for (int mt = 0; mt < 4; ++mt)
#pragma unroll
            for (int nt = 0; nt < 4; ++nt) {
                f4_t acc = {biv[nt], biv[nt], biv[nt], biv[nt]};
                acc = __builtin_amdgcn_mfma_f32_16x16x32_bf16(aF[mt][0], wi[0][nt], acc, 0, 0, 0);
                acc = __builtin_amdgcn_mfma_f32_16x16x32_bf16(aF[mt][1], wi[1][nt], acc, 0, 0, 0);
#pragma unroll
                for (int reg = 0; reg < 4; ++reg) {
                    int r = mt * 16 + quad * 4 + reg;
                    if (r < rows) v[(size_t)(a0 + r) * FDIM + nt * 16 + l15] = sp(acc[reg]);
                }
            }
#pragma unroll
        for (int mt = 0; mt < 4; ++mt)
#pragma unroll
            for (int nt = 0; nt < 4; ++nt) {
                f4_t acc = {bjv[nt], bjv[nt], bjv[nt], bjv[nt]};
                acc = __builtin_amdgcn_mfma_f32_16x16x32_bf16(aF[mt][0], wj[0][nt], acc, 0, 0, 0);
                acc = __builtin_amdgcn_mfma_f32_16x16x32_bf16(aF[mt][1], wj[1][nt], acc, 0, 0, 0);
#pragma unroll
                for (int reg = 0; reg < 4; ++reg) {
                    int r = mt * 16 + quad * 4 + reg;
                    if (r < rows) y[(size_t)(a0 + r) * FDIM + nt * 16 + l15] = sp(acc[reg]);
                }
            }
    }
}

// ---------------- k_post: fused 3 residual blocks + final projection (MFMA) ---
__global__ __launch_bounds__(256) void k_post(
    const __bf16* __restrict__ wf,
    const float* __restrict__ rb1, const float* __restrict__ rb2,
    const float* __restrict__ bv,
    float* __restrict__ v, int N)
{
    __shared__ float tile[4][64 * LTS];
    const int lane = threadIdx.x & 63;
    const int wv = threadIdx.x >> 6;
    float* T = tile[wv];
    const int l15 = lane & 15, quad = lane >> 4;

    float b1v[3][4], b2v[3][4], bvv[4];
#pragma unroll
    for (int l = 0; l < 3; ++l)
#pragma unroll
        for (int nt = 0; nt < 4; ++nt) {
            b1v[l][nt] = rb1[l * FDIM + nt * 16 + l15];
            b2v[l][nt] = rb2[l * FDIM + nt * 16 + l15];
        }
#pragma unroll
    for (int nt = 0; nt < 4; ++nt) bvv[nt] = bv[nt * 16 + l15];

    const int nTiles = (N + 63) >> 6;
    for (int t = blockIdx.x * 4 + wv; t < nTiles; t += gridDim.x * 4) {
        const int a0 = t << 6;
        const int rows = min(64, N - a0);
        tile_in(T, v, a0, rows, lane);
        float vC[16][4];
#pragma unroll
        for (int mt = 0; mt < 4; ++mt)
#pragma unroll
            for (int nt = 0; nt < 4; ++nt)
#pragma unroll
                for (int reg = 0; reg < 4; ++reg)
                    vC[mt * 4 + nt][reg] =
                        T[(mt * 16 + quad * 4 + reg) * LTS + nt * 16 + l15];

        for (int l = 0; l < 3; ++l) {
            const bf8_t* w1f = (const bf8_t*)(wf + (size_t)(2 * l) * 4096);
            const bf8_t* w2f = (const bf8_t*)(wf + (size_t)(2 * l + 1) * 4096);
            bf8_t aF[4][2];
            build_a(T, lane, false, aF);
#pragma unroll
            for (int mt = 0; mt < 4; ++mt)
#pragma unroll
                for (int nt = 0; nt < 4; ++nt) {
                    f4_t acc = {b1v[l][nt], b1v[l][nt], b1v[l][nt], b1v[l][nt]};
                    acc = __builtin_amdgcn_mfma_f32_16x16x32_bf16(aF[mt][0], w1f[(0 * 4 + nt) * 64 + lane], acc, 0, 0, 0);
                    acc = __builtin_amdgcn_mfma_f32_16x16x32_bf16(aF[mt][1], w1f[(1 * 4 + nt) * 64 + lane], acc, 0, 0, 0);
#pragma unroll
                    for (int reg = 0; reg < 4; ++reg)
                        T[(mt * 16 + quad * 4 + reg) * LTS + nt * 16 + l15] = sp(acc[reg]);
                }
            bf8_t hF[4][2];
            build_a(T, lane, false, hF);
#pragma unroll
            for (int mt = 0; mt < 4; ++mt)
#pragma unroll
                for (int nt = 0; nt < 4; ++nt) {
                    f4_t acc = {b2v[l][nt], b2v[l][nt], b2v[l][nt], b2v[l][nt]};
                    acc = __builtin_amdgcn_mfma_f32_16x16x32_bf16(hF[mt][0], w2f[(0 * 4 + nt) * 64 + lane], acc, 0, 0, 0);
                    acc = __builtin_amdgcn_mfma_f32_16x16x32_bf16(hF[mt][1], w2f[(1 * 4 + nt) * 64 + lane], acc, 0, 0, 0);
#pragma unroll
                    for (int reg = 0; reg < 4; ++reg)
                        vC[mt * 4 + nt][reg] += acc[reg];
                }
            if (l < 2) {
#pragma unroll
                for (int mt = 0; mt < 4; ++mt)
#pragma unroll
                    for (int nt = 0; nt < 4; ++nt)
#pragma unroll
                        for (int reg = 0; reg < 4; ++reg)
                            T[(mt * 16 + quad * 4 + reg) * LTS + nt * 16 + l15] =
                                vC[mt * 4 + nt][reg];
            }
        }
#pragma unroll
        for (int mt = 0; mt < 4; ++mt)
#pragma unroll
            for (int nt = 0; nt < 4; ++nt)
#pragma unroll
                for (int reg = 0; reg < 4; ++reg)
                    T[(mt * 16 + quad * 4 + reg) * LTS + nt * 16 + l15] =
                        sp(vC[mt * 4 + nt][reg]);
        bf8_t fF[4][2];
        build_a(T, lane, false, fF);
        const bf8_t* wvf = (const bf8_t*)(wf + (size_t)6 * 4096);
#pragma unroll
        for (int mt = 0; mt < 4; ++mt)
#pragma unroll
            for (int nt = 0; nt < 4; ++nt) {
                f4_t acc = {bvv[nt], bvv[nt], bvv[nt], bvv[nt]};
                acc = __builtin_amdgcn_mfma_f32_16x16x32_bf16(fF[mt][0], wvf[(0 * 4 + nt) * 64 + lane], acc, 0, 0, 0);
                acc = __builtin_amdgcn_mfma_f32_16x16x32_bf16(fF[mt][1], wvf[(1 * 4 + nt) * 64 + lane], acc, 0, 0, 0);
#pragma unroll
                for (int reg = 0; reg < 4; ++reg) {
                    int r = mt * 16 + quad * 4 + reg;
                    if (r < rows) v[(size_t)(a0 + r) * FDIM + nt * 16 + l15] = acc[reg];
                }
            }
    }
}

// ---------------- scan / scatter (counters padded to CPAD ints) ---------------
__global__ __launch_bounds__(256) void k_scan_a(
    const int* __restrict__ cntP, int* __restrict__ part, int N)
{
    __shared__ int red[256];
    int b = blockIdx.x, t = threadIdx.x;
    int base = b * 1024 + t * 4;
    int s = 0;
#pragma unroll
    for (int i = 0; i < 4; ++i) { int a = base + i; if (a < N) s += cntP[(size_t)a * CPAD]; }
    red[t] = s; __syncthreads();
    for (int off = 128; off > 0; off >>= 1) {
        if (t < off) red[t] += red[t + off];
        __syncthreads();
    }
    if (t == 0) part[b] = red[0];
}

__global__ __launch_bounds__(256) void k_scan_b(int* __restrict__ part, int nPart)
{
    __shared__ int lds[256];
    int t = threadIdx.x;
    int base = t * 4;
    int v[4]; int s = 0;
#pragma unroll
    for (int i = 0; i < 4; ++i) { v[i] = (base + i < nPart) ? part[base + i] : 0; s += v[i]; }
    lds[t] = s; __syncthreads();
    int run = s;
    for (int off = 1; off < 256; off <<= 1) {
        int x = (t >= off) ? lds[t - off] : 0;
        __syncthreads();
        lds[t] += x;
        __syncthreads();
    }
    int excl = lds[t] - run;
#pragma unroll
    for (int i = 0; i < 4; ++i) { if (base + i < nPart) { part[base + i] = excl; excl += v[i]; } }
}

// NOTE: cntP and cursorP alias (cursor reuses the padded cnt array). Per element
// a, the read of cntP happens before the write of cursorP in the same thread.
__global__ __launch_bounds__(256) void k_scan_c(
    const int* cntP, const int* __restrict__ part,
    int* __restrict__ start, int* cursorP, int N, int P)
{
    __shared__ int lds[256];
    int b = blockIdx.x, t = threadIdx.x;
    int base = b * 1024 + t * 4;
    int v[4]; int s = 0;
#pragma unroll
    for (int i = 0; i < 4; ++i) { int a = base + i; v[i] = (a < N) ? cntP[(size_t)a * CPAD] : 0; s += v[i]; }
    lds[t] = s; __syncthreads();
    int run = s;
    for (int off = 1; off < 256; off <<= 1) {
        int x = (t >= off) ? lds[t - off] : 0;
        __syncthreads();
        lds[t] += x;
        __syncthreads();
    }
    int pre = part[b] + (lds[t] - run);
#pragma unroll
    for (int i = 0; i < 4; ++i) {
        int a = base + i;
        if (a < N) { start[a] = pre; cursorP[(size_t)a * CPAD] = pre; pre += v[i]; }
    }
    if (b == 0 && t == 0) start[N] = P;
}

__global__ __launch_bounds__(256) void k_scatter(
    const int* __restrict__ pidx, int* __restrict__ cursorP,
    int2* __restrict__ sorted, int P)
{
    int t = blockIdx.x * blockDim.x + threadIdx.x;
    int n = gridDim.x * blockDim.x;
    int p = t;
    for (; p + 3 * n < P; p += 4 * n) {
        int i0 = pidx[p],         j0 = pidx[P + p];
        int i1 = pidx[p + n],     j1 = pidx[P + p + n];
        int i2 = pidx[p + 2 * n], j2 = pidx[P + p + 2 * n];
        int i3 = pidx[p + 3 * n], j3 = pidx[P + p + 3 * n];
        int q0 = atomicAdd(&cursorP[(size_t)i0 * CPAD], 1);
        int q1 = atomicAdd(&cursorP[(size_t)i1 * CPAD], 1);
        int q2 = atomicAdd(&cursorP[(size_t)i2 * CPAD], 1);
        int q3 = atomicAdd(&cursorP[(size_t)i3 * CPAD], 1);
        sorted[q0] = make_int2(p, j0);
        sorted[q1] = make_int2(p + n, j1);
        sorted[q2] = make_int2(p + 2 * n, j2);
        sorted[q3] = make_int2(p + 3 * n, j3);
    }
    for (; p < P; p += n) {
        int i = pidx[p], j = pidx[P + p];
        int pos = atomicAdd(&cursorP[(size_t)i * CPAD], 1);
        sorted[pos] = make_int2(p, j);
    }
}

// ---------------- k_seg -------------------------------------------------------
// summed[a,c] = sum_r G[c,r] * t[r],  t[r] = sum_{p in seg(a)} f_ij[p,r]*y[j_p,c]
// Block of <=64 sorted entries loaded once per wave (coalesced), (p,j) extracted
// via v_readlane. 8 independent y-gathers in flight per inner group.
__global__ __launch_bounds__(256) void k_seg(
    const int2* __restrict__ sorted, const int* __restrict__ start,
    const float* __restrict__ f_ij, const float* __restrict__ G,
    const float* __restrict__ y, float* __restrict__ v, int N)
{
    const int c = threadIdx.x & 63;
    const int w = __builtin_amdgcn_readfirstlane((blockIdx.x << 2) | (threadIdx.x >> 6));
    const int nw = gridDim.x << 2;

    float g[16];
    {
        const float4* gp = (const float4*)(G + c * RDIM);
        float4 g0 = gp[0], g1 = gp[1], g2 = gp[2], g3 = gp[3];
        g[0] = g0.x;  g[1] = g0.y;  g[2] = g0.z;  g[3] = g0.w;
        g[4] = g1.x;  g[5] = g1.y;  g[6] = g1.z;  g[7] = g1.w;
        g[8] = g2.x;  g[9] = g2.y;  g[10] = g2.z; g[11] = g2.w;
        g[12] = g3.x; g[13] = g3.y; g[14] = g3.z; g[15] = g3.w;
    }

    for (int a = w; a < N; a += nw) {
        const int s = start[a], e = start[a + 1];
        float vold = v[(size_t)a * FDIM + c];   // hoist RMW read over the pair loop
        float t[16];
#pragma unroll
        for (int r = 0; r < 16; ++r) t[r] = 0.0f;

        for (int base = s; base < e; base += 64) {
            const int nn = (e - base < 64) ? (e - base) : 64;
            const int li = (c < nn) ? c : (nn - 1);
            const int2 E = sorted[base + li];
            const int pk = E.x, jk = E.y;

            int k = 0;
            for (; k + 8 <= nn; k += 8) {
                int pp[8], jj[8];
#pragma unroll
                for (int u = 0; u < 8; ++u) {
                    pp[u] = __builtin_amdgcn_readlane(pk, k + u);
                    jj[u] = __builtin_amdgcn_readlane(jk, k + u);
                }
                float yv[8];
#pragma unroll
                for (int u = 0; u < 8; ++u)
                    yv[u] = y[(size_t)jj[u] * FDIM + c];
#pragma unroll
                for (int u = 0; u < 8; ++u) {
                    const float* f = f_ij + (size_t)pp[u] * RDIM;
#pragma unroll
                    for (int r = 0; r < 16; ++r) t[r] = fmaf(f[r], yv[u], t[r]);
                }
            }
            for (; k + 4 <= nn; k += 4) {
                int pp[4], jj[4];
#pragma unroll
                for (int u = 0; u < 4; ++u) {
                    pp[u] = __builtin_amdgcn_readlane(pk, k + u);
                    jj[u] = __builtin_amdgcn_readlane(jk, k + u);
                }
                float yv[4];
#pragma unroll
                for (int u = 0; u < 4; ++u)
                    yv[u] = y[(size_t)jj[u] * FDIM + c];
#pragma unroll
                for (int u = 0; u < 4; ++u) {
                    const float* f = f_ij + (size_t)pp[u] * RDIM;
#pragma unroll
                    for (int r = 0; r < 16; ++r) t[r] = fmaf(f[r], yv[u], t[r]);
                }
            }
            for (; k < nn; ++k) {
                const int p0 = __builtin_amdgcn_readlane(pk, k);
                const int j0 = __builtin_amdgcn_readlane(jk, k);
                float y0 = y[(size_t)j0 * FDIM + c];
                const float* f0 = f_ij + (size_t)p0 * RDIM;
#pragma unroll
                for (int r = 0; r < 16; ++r) t[r] = fmaf(f0[r], y0, t[r]);
            }
        }

        float acc0 = 0.f, acc1 = 0.f, acc2 = 0.f, acc3 = 0.f;
#pragma unroll
        for (int r = 0; r < 16; r += 4) {
            acc0 = fmaf(g[r + 0], t[r + 0], acc0);
            acc1 = fmaf(g[r + 1], t[r + 1], acc1);
            acc2 = fmaf(g[r + 2], t[r + 2], acc2);
            acc3 = fmaf(g[r + 3], t[r + 3], acc3);
        }
        v[(size_t)a * FDIM + c] = vold + (acc0 + acc1) + (acc2 + acc3);
    }
}

extern "C" void kernel_launch(void* const* d_in, const int* in_sizes, int n_in,
                              void* d_out, int out_size, void* d_ws, size_t ws_size,
                              hipStream_t stream)
{
    const int*   pidx = (const int*)d_in[0];    // [2, P]
    const float* f_ij = (const float*)d_in[1];  // [P, 1, R]
    const float* emb  = (const float*)d_in[3];  // [N, F]
    const float* G    = (const float*)d_in[4];  // [F, R]
    const float* Wi   = (const float*)d_in[5];
    const float* bi   = (const float*)d_in[6];
    const float* Wj   = (const float*)d_in[7];
    const float* bj   = (const float*)d_in[8];
    const float* rW1  = (const float*)d_in[9];
    const float* rb1  = (const float*)d_in[10];
    const float* rW2  = (const float*)d_in[11];
    const float* rb2  = (const float*)d_in[12];
    const float* Wv   = (const float*)d_in[13];
    const float* bv   = (const float*)d_in[14];

    const int P = in_sizes[0] / 2;
    const int N = in_sizes[3] / FDIM;

    float* v = (float*)d_out;

    // workspace layout
    char* ws = (char*)d_ws;
    size_t off = 0;
    float*  y      = (float*)(ws + off);  off += (size_t)N * FDIM * 4;
    int*    cntP   = (int*)(ws + off);    off += (size_t)N * CPAD * 4;  // padded counters; reused as cursor
    int*    start  = (int*)(ws + off);    off += (size_t)(N + 1) * 4;
    off = (off + 15) & ~(size_t)15;
    int*    part   = (int*)(ws + off);    off += (size_t)4096 * 4;
    off = (off + 15) & ~(size_t)15;
    int2*   sorted = (int2*)(ws + off);   off += (size_t)P * 8;
    off = (off + 15) & ~(size_t)15;
    __bf16* wf     = (__bf16*)(ws + off); off += (size_t)9 * 4096 * 2;
    // wf matrices: 0=Wi 1=Wj 2=W1_0 3=W2_0 4=W1_1 5=W2_1 6=W1_2 7=W2_2 8=Wv

    const int nPart = (N + 1023) / 1024;
    const int nTiles = (N + 63) >> 6;
    const int gTiles = (nTiles + 3) / 4;   // 1 tile per wave

    dim3 blk(256);
    hipMemsetAsync(cntP, 0, (size_t)N * CPAD * 4, stream);
    k_prep<<<9, blk, 0, stream>>>(Wi, Wj, rW1, rW2, rW1 + 4096, rW2 + 4096,
                                  rW1 + 8192, rW2 + 8192, Wv, wf);
    k_hist<<<2048, blk, 0, stream>>>(pidx, cntP, P);
    k_atoms<<<gTiles, blk, 0, stream>>>(emb, wf, bi, bj, v, y, N);
    k_scan_a<<<nPart, blk, 0, stream>>>(cntP, part, N);
    k_scan_b<<<1, blk, 0, stream>>>(part, nPart);
    k_scan_c<<<nPart, blk, 0, stream>>>(cntP, part, start, cntP, N, P);
    k_scatter<<<2048, blk, 0, stream>>>(pidx, cntP, sorted, P);
    k_seg<<<4096, blk, 0, stream>>>(sorted, start, f_ij, G, y, v, N);
    k_post<<<gTiles, blk, 0, stream>>>(wf + (size_t)2 * 4096, rb1, rb2, bv, v, N);
}

// Round 4
// 634.254 us; speedup vs baseline: 1.2118x; 1.2118x over previous
//
#include <hip/hip_runtime.h>
#include <math.h>

#define FDIM 64
#define RDIM 16
#define LN2F 0.69314718055994530942f
#define LTS 68       // LDS tile row stride (floats)
#define NBINR 14336  // bins per range-pass (56KB LDS), 7 ranges cover 100K atoms
#define NCHUNK 64    // pair chunks (Cmat[chunk][bin] aliases y: 64*N ints == N*64 floats)

typedef __bf16 bf8_t __attribute__((ext_vector_type(8)));
typedef float  f4_t  __attribute__((ext_vector_type(4)));

// Numerically stable softplus (fast intrinsics)
__device__ __forceinline__ float sp(float x) {
    return fmaxf(x, 0.0f) + __logf(1.0f + __expf(-fabsf(x)));
}

// ---------------- weight prep: fp32 [k][c] -> bf16 B-fragment layout ----------
__global__ __launch_bounds__(256) void k_prep(
    const float* s0, const float* s1, const float* s2, const float* s3,
    const float* s4, const float* s5, const float* s6, const float* s7,
    const float* s8, __bf16* __restrict__ dst)
{
    const float* srcs[9] = {s0, s1, s2, s3, s4, s5, s6, s7, s8};
    const float* W = srcs[blockIdx.x];
    __bf16* d = dst + (size_t)blockIdx.x * 4096;
    for (int slot = threadIdx.x; slot < 512; slot += 256) {
        int f = slot >> 6, l = slot & 63;
        int kt = f >> 2, nt = f & 3;
        int row0 = kt * 32 + (l >> 4) * 8;
        int col = nt * 16 + (l & 15);
#pragma unroll
        for (int j = 0; j < 8; ++j)
            d[slot * 8 + j] = (__bf16)W[(row0 + j) * FDIM + col];
    }
}

// ---------------- hist: LDS-private per-(chunk,range) histograms --------------
// NO global atomics (device-coherent atomic path is ~4 ops/cy device-wide).
// Block (chunk, range): LDS-histogram chunk's pairs whose i is in range, then
// coalesced non-atomic write of partial counts to Cmat[chunk][bin].
__global__ __launch_bounds__(256) void k_hist2(
    const int* __restrict__ idx_i, int* __restrict__ Cmat,
    int P, int N, int nRange)
{
    __shared__ int h[NBINR];
    const int chunk = blockIdx.x / nRange;
    const int range = blockIdx.x % nRange;
    const int lo = range * NBINR;
    const int nb = min(NBINR, N - lo);
    for (int u = threadIdx.x; u < NBINR; u += 256) h[u] = 0;
    __syncthreads();

    const int chunkSz = (P + NCHUNK - 1) / NCHUNK;
    const int cs = chunk * chunkSz;
    const int ce = min(P, cs + chunkSz);
    int p = cs + threadIdx.x;
    for (; p + 768 < ce; p += 1024) {
        int i0 = idx_i[p];
        int i1 = idx_i[p + 256];
        int i2 = idx_i[p + 512];
        int i3 = idx_i[p + 768];
        unsigned u0 = (unsigned)(i0 - lo);
        unsigned u1 = (unsigned)(i1 - lo);
        unsigned u2 = (unsigned)(i2 - lo);
        unsigned u3 = (unsigned)(i3 - lo);
        if (u0 < (unsigned)nb) atomicAdd(&h[u0], 1);
        if (u1 < (unsigned)nb) atomicAdd(&h[u1], 1);
        if (u2 < (unsigned)nb) atomicAdd(&h[u2], 1);
        if (u3 < (unsigned)nb) atomicAdd(&h[u3], 1);
    }
    for (; p < ce; p += 256) {
        unsigned u = (unsigned)(idx_i[p] - lo);
        if (u < (unsigned)nb) atomicAdd(&h[u], 1);
    }
    __syncthreads();
    for (int u = threadIdx.x; u < nb; u += 256)
        Cmat[(size_t)chunk * N + lo + u] = h[u];
}

// ---------------- scanR: Cmat -> per-chunk exclusive bases (in place) + totals
// Per bin: run over chunks; Cmat[c][b] becomes sum of counts of chunks < c.
// Register-only, all row accesses coalesced.
__global__ __launch_bounds__(256) void k_scanR(
    int* __restrict__ Cmat, int* __restrict__ tot, int N)
{
    const int bA = blockIdx.x * 512 + threadIdx.x;
    const int bB = bA + 256;
    const bool okA = bA < N, okB = bB < N;
    int runA = 0, runB = 0;
    for (int c = 0; c < NCHUNK; ++c) {
        const size_t base = (size_t)c * N;
        if (okA) { int val = Cmat[base + bA]; Cmat[base + bA] = runA; runA += val; }
        if (okB) { int val = Cmat[base + bB]; Cmat[base + bB] = runB; runB += val; }
    }
    if (okA) tot[bA] = runA;
    if (okB) tot[bB] = runB;
}

// ---------------- tile in: coalesced global -> wave-private LDS ----------------
__device__ __forceinline__ void tile_in(float* T, const float* __restrict__ src,
                                        int a0, int rows, int lane)
{
#pragma unroll 4
    for (int i = 0; i < 16; ++i) {
        int r = i * 4 + (lane >> 4);
        int col = (lane & 15) * 4;
        float4 val = make_float4(0.f, 0.f, 0.f, 0.f);
        if (r < rows) val = *(const float4*)&src[(size_t)(a0 + r) * FDIM + col];
        *(float4*)&T[r * LTS + col] = val;
    }
}

// build A-fragments (bf16) for a 64x64 LDS tile: aF[mt][kt]
__device__ __forceinline__ void build_a(const float* T, int lane, bool actLn2,
                                        bf8_t (&aF)[4][2])
{
    const int l15 = lane & 15, quad = lane >> 4;
#pragma unroll
    for (int mt = 0; mt < 4; ++mt) {
#pragma unroll
        for (int kt = 0; kt < 2; ++kt) {
            const float* rp = &T[(mt * 16 + l15) * LTS + kt * 32 + quad * 8];
            float4 u0 = *(const float4*)rp;
            float4 u1 = *(const float4*)(rp + 4);
            float e[8] = {u0.x, u0.y, u0.z, u0.w, u1.x, u1.y, u1.z, u1.w};
            bf8_t f;
#pragma unroll
            for (int j = 0; j < 8; ++j) {
                float t = actLn2 ? (sp(e[j]) - LN2F) : e[j];
                f[j] = (__bf16)t;
            }
            aF[mt][kt] = f;
        }
    }
}

// ---------------- k_atoms: x=sp(emb)-ln2; v=sp(x@Wi+bi); y=sp(x@Wj+bj) --------
__global__ __launch_bounds__(256) void k_atoms(
    const float* __restrict__ emb, const __bf16* __restrict__ wf,
    const float* __restrict__ bi, const float* __restrict__ bj,
    float* __restrict__ v, float* __restrict__ y, int N)
{
    __shared__ float tile[4][64 * LTS];
    const int lane = threadIdx.x & 63;
    const int wv = threadIdx.x >> 6;
    float* T = tile[wv];
    const int l15 = lane & 15, quad = lane >> 4;

    const bf8_t* wiF = (const bf8_t*)wf;            // matrix 0
    const bf8_t* wjF = (const bf8_t*)(wf + 4096);   // matrix 1
    bf8_t wi[2][4], wj[2][4];
#pragma unroll
    for (int kt = 0; kt < 2; ++kt)
#pragma unroll
        for (int nt = 0; nt < 4; ++nt) {
            wi[kt][nt] = wiF[(kt * 4 + nt) * 64 + lane];
            wj[kt][nt] = wjF[(kt * 4 + nt) * 64 + lane];
        }
    float biv[4], bjv[4];
#pragma unroll
    for (int nt = 0; nt < 4; ++nt) {
        biv[nt] = bi[nt * 16 + l15];
        bjv[nt] = bj[nt * 16 + l15];
    }

    const int nTiles = (N + 63) >> 6;
    for (int t = blockIdx.x * 4 + wv; t < nTiles; t += gridDim.x * 4) {
        const int a0 = t << 6;
        const int rows = min(64, N - a0);
        tile_in(T, emb, a0, rows, lane);
        bf8_t aF[4][2];
        build_a(T, lane, true, aF);
#pragma unroll
        for (int mt = 0; mt < 4; ++mt)
#pragma unroll
            for (int nt = 0; nt < 4; ++nt) {
                f4_t acc = {biv[nt], biv[nt], biv[nt], biv[nt]};
                acc = __builtin_amdgcn_mfma_f32_16x16x32_bf16(aF[mt][0], wi[0][nt], acc, 0, 0, 0);
                acc = __builtin_amdgcn_mfma_f32_16x16x32_bf16(aF[mt][1], wi[1][nt], acc, 0, 0, 0);
#pragma unroll
                for (int reg = 0; reg < 4; ++reg) {
                    int r = mt * 16 + quad * 4 + reg;
                    if (r < rows) v[(size_t)(a0 + r) * FDIM + nt * 16 + l15] = sp(acc[reg]);
                }
            }
#pragma unroll
        for (int mt = 0; mt < 4; ++mt)
#pragma unroll
            for (int nt = 0; nt < 4; ++nt) {
                f4_t acc = {bjv[nt], bjv[nt], bjv[nt], bjv[nt]};
                acc = __builtin_amdgcn_mfma_f32_16x16x32_bf16(aF[mt][0], wj[0][nt], acc, 0, 0, 0);
                acc = __builtin_amdgcn_mfma_f32_16x16x32_bf16(aF[mt][1], wj[1][nt], acc, 0, 0, 0);
#pragma unroll
                for (int reg = 0; reg < 4; ++reg) {
                    int r = mt * 16 + quad * 4 + reg;
                    if (r < rows) y[(size_t)(a0 + r) * FDIM + nt * 16 + l15] = sp(acc[reg]);
                }
            }
    }
}

// ---------------- k_post: fused 3 residual blocks + final projection (MFMA) ---
__global__ __launch_bounds__(256) void k_post(
    const __bf16* __restrict__ wf,
    const float* __restrict__ rb1, const float* __restrict__ rb2,
    const float* __restrict__ bv,
    float* __restrict__ v, int N)
{
    __shared__ float tile[4][64 * LTS];
    const int lane = threadIdx.x & 63;
    const int wv = threadIdx.x >> 6;
    float* T = tile[wv];
    const int l15 = lane & 15, quad = lane >> 4;

    float b1v[3][4], b2v[3][4], bvv[4];
#pragma unroll
    for (int l = 0; l < 3; ++l)
#pragma unroll
        for (int nt = 0; nt < 4; ++nt) {
            b1v[l][nt] = rb1[l * FDIM + nt * 16 + l15];
            b2v[l][nt] = rb2[l * FDIM + nt * 16 + l15];
        }
#pragma unroll
    for (int nt = 0; nt < 4; ++nt) bvv[nt] = bv[nt * 16 + l15];

    const int nTiles = (N + 63) >> 6;
    for (int t = blockIdx.x * 4 + wv; t < nTiles; t += gridDim.x * 4) {
        const int a0 = t << 6;
        const int rows = min(64, N - a0);
        tile_in(T, v, a0, rows, lane);
        float vC[16][4];
#pragma unroll
        for (int mt = 0; mt < 4; ++mt)
#pragma unroll
            for (int nt = 0; nt < 4; ++nt)
#pragma unroll
                for (int reg = 0; reg < 4; ++reg)
                    vC[mt * 4 + nt][reg] =
                        T[(mt * 16 + quad * 4 + reg) * LTS + nt * 16 + l15];

        for (int l = 0; l < 3; ++l) {
            const bf8_t* w1f = (const bf8_t*)(wf + (size_t)(2 * l) * 4096);
            const bf8_t* w2f = (const bf8_t*)(wf + (size_t)(2 * l + 1) * 4096);
            bf8_t aF[4][2];
            build_a(T, lane, false, aF);
#pragma unroll
            for (int mt = 0; mt < 4; ++mt)
#pragma unroll
                for (int nt = 0; nt < 4; ++nt) {
                    f4_t acc = {b1v[l][nt], b1v[l][nt], b1v[l][nt], b1v[l][nt]};
                    acc = __builtin_amdgcn_mfma_f32_16x16x32_bf16(aF[mt][0], w1f[(0 * 4 + nt) * 64 + lane], acc, 0, 0, 0);
                    acc = __builtin_amdgcn_mfma_f32_16x16x32_bf16(aF[mt][1], w1f[(1 * 4 + nt) * 64 + lane], acc, 0, 0, 0);
#pragma unroll
                    for (int reg = 0; reg < 4; ++reg)
                        T[(mt * 16 + quad * 4 + reg) * LTS + nt * 16 + l15] = sp(acc[reg]);
                }
            bf8_t hF[4][2];
            build_a(T, lane, false, hF);
#pragma unroll
            for (int mt = 0; mt < 4; ++mt)
#pragma unroll
                for (int nt = 0; nt < 4; ++nt) {
                    f4_t acc = {b2v[l][nt], b2v[l][nt], b2v[l][nt], b2v[l][nt]};
                    acc = __builtin_amdgcn_mfma_f32_16x16x32_bf16(hF[mt][0], w2f[(0 * 4 + nt) * 64 + lane], acc, 0, 0, 0);
                    acc = __builtin_amdgcn_mfma_f32_16x16x32_bf16(hF[mt][1], w2f[(1 * 4 + nt) * 64 + lane], acc, 0, 0, 0);
#pragma unroll
                    for (int reg = 0; reg < 4; ++reg)
                        vC[mt * 4 + nt][reg] += acc[reg];
                }
            if (l < 2) {
#pragma unroll
                for (int mt = 0; mt < 4; ++mt)
#pragma unroll
                    for (int nt = 0; nt < 4; ++nt)
#pragma unroll
                        for (int reg = 0; reg < 4; ++reg)
                            T[(mt * 16 + quad * 4 + reg) * LTS + nt * 16 + l15] =
                                vC[mt * 4 + nt][reg];
            }
        }
#pragma unroll
        for (int mt = 0; mt < 4; ++mt)
#pragma unroll
            for (int nt = 0; nt < 4; ++nt)
#pragma unroll
                for (int reg = 0; reg < 4; ++reg)
                    T[(mt * 16 + quad * 4 + reg) * LTS + nt * 16 + l15] =
                        sp(vC[mt * 4 + nt][reg]);
        bf8_t fF[4][2];
        build_a(T, lane, false, fF);
        const bf8_t* wvf = (const bf8_t*)(wf + (size_t)6 * 4096);
#pragma unroll
        for (int mt = 0; mt < 4; ++mt)
#pragma unroll
            for (int nt = 0; nt < 4; ++nt) {
                f4_t acc = {bvv[nt], bvv[nt], bvv[nt], bvv[nt]};
                acc = __builtin_amdgcn_mfma_f32_16x16x32_bf16(fF[mt][0], wvf[(0 * 4 + nt) * 64 + lane], acc, 0, 0, 0);
                acc = __builtin_amdgcn_mfma_f32_16x16x32_bf16(fF[mt][1], wvf[(1 * 4 + nt) * 64 + lane], acc, 0, 0, 0);
#pragma unroll
                for (int reg = 0; reg < 4; ++reg) {
                    int r = mt * 16 + quad * 4 + reg;
                    if (r < rows) v[(size_t)(a0 + r) * FDIM + nt * 16 + l15] = acc[reg];
                }
            }
    }
}

// ---------------- global scan over per-bin totals -----------------------------
__global__ __launch_bounds__(256) void k_scan_a(
    const int* __restrict__ cnt, int* __restrict__ part, int N)
{
    __shared__ int red[256];
    int b = blockIdx.x, t = threadIdx.x;
    int base = b * 1024 + t * 4;
    int s = 0;
#pragma unroll
    for (int i = 0; i < 4; ++i) { int a = base + i; if (a < N) s += cnt[a]; }
    red[t] = s; __syncthreads();
    for (int off = 128; off > 0; off >>= 1) {
        if (t < off) red[t] += red[t + off];
        __syncthreads();
    }
    if (t == 0) part[b] = red[0];
}

__global__ __launch_bounds__(256) void k_scan_b(int* __restrict__ part, int nPart)
{
    __shared__ int lds[256];
    int t = threadIdx.x;
    int base = t * 4;
    int v[4]; int s = 0;
#pragma unroll
    for (int i = 0; i < 4; ++i) { v[i] = (base + i < nPart) ? part[base + i] : 0; s += v[i]; }
    lds[t] = s; __syncthreads();
    int run = s;
    for (int off = 1; off < 256; off <<= 1) {
        int x = (t >= off) ? lds[t - off] : 0;
        __syncthreads();
        lds[t] += x;
        __syncthreads();
    }
    int excl = lds[t] - run;
#pragma unroll
    for (int i = 0; i < 4; ++i) { if (base + i < nPart) { part[base + i] = excl; excl += v[i]; } }
}

__global__ __launch_bounds__(256) void k_scan_c(
    const int* __restrict__ cnt, const int* __restrict__ part,
    int* __restrict__ start, int N, int P)
{
    __shared__ int lds[256];
    int b = blockIdx.x, t = threadIdx.x;
    int base = b * 1024 + t * 4;
    int v[4]; int s = 0;
#pragma unroll
    for (int i = 0; i < 4; ++i) { int a = base + i; v[i] = (a < N) ? cnt[a] : 0; s += v[i]; }
    lds[t] = s; __syncthreads();
    int run = s;
    for (int off = 1; off < 256; off <<= 1) {
        int x = (t >= off) ? lds[t - off] : 0;
        __syncthreads();
        lds[t] += x;
        __syncthreads();
    }
    int pre = part[b] + (lds[t] - run);
#pragma unroll
    for (int i = 0; i < 4; ++i) {
        int a = base + i;
        if (a < N) { start[a] = pre; pre += v[i]; }
    }
    if (b == 0 && t == 0) start[N] = P;
}

// ---------------- scatter: LDS cursors, LDS atomic returns --------------------
// Block (chunk, range): cursor[bin] = start[bin] + Cmat[chunk][bin] preloaded
// into LDS; unique slots come from LDS atomicAdd. Zero global atomics.
__global__ __launch_bounds__(256) void k_scatter2(
    const int* __restrict__ pidx, const int* __restrict__ Cmat,
    const int* __restrict__ start, int2* __restrict__ sorted,
    int P, int N, int nRange)
{
    __shared__ int cur[NBINR];
    const int chunk = blockIdx.x / nRange;
    const int range = blockIdx.x % nRange;
    const int lo = range * NBINR;
    const int nb = min(NBINR, N - lo);
    for (int u = threadIdx.x; u < nb; u += 256)
        cur[u] = start[lo + u] + Cmat[(size_t)chunk * N + lo + u];
    __syncthreads();

    const int chunkSz = (P + NCHUNK - 1) / NCHUNK;
    const int cs = chunk * chunkSz;
    const int ce = min(P, cs + chunkSz);
    int p = cs + threadIdx.x;
    for (; p + 768 < ce; p += 1024) {
        int i0 = pidx[p];
        int i1 = pidx[p + 256];
        int i2 = pidx[p + 512];
        int i3 = pidx[p + 768];
        int j0 = pidx[P + p];
        int j1 = pidx[P + p + 256];
        int j2 = pidx[P + p + 512];
        int j3 = pidx[P + p + 768];
        unsigned u0 = (unsigned)(i0 - lo);
        unsigned u1 = (unsigned)(i1 - lo);
        unsigned u2 = (unsigned)(i2 - lo);
        unsigned u3 = (unsigned)(i3 - lo);
        if (u0 < (unsigned)nb) { int pos = atomicAdd(&cur[u0], 1); sorted[pos] = make_int2(p, j0); }
        if (u1 < (unsigned)nb) { int pos = atomicAdd(&cur[u1], 1); sorted[pos] = make_int2(p + 256, j1); }
        if (u2 < (unsigned)nb) { int pos = atomicAdd(&cur[u2], 1); sorted[pos] = make_int2(p + 512, j2); }
        if (u3 < (unsigned)nb) { int pos = atomicAdd(&cur[u3], 1); sorted[pos] = make_int2(p + 768, j3); }
    }
    for (; p < ce; p += 256) {
        int i = pidx[p];
        unsigned u = (unsigned)(i - lo);
        if (u < (unsigned)nb) {
            int j = pidx[P + p];
            int pos = atomicAdd(&cur[u], 1);
            sorted[pos] = make_int2(p, j);
        }
    }
}

// ---------------- k_seg -------------------------------------------------------
// summed[a,c] = sum_r G[c,r] * t[r],  t[r] = sum_{p in seg(a)} f_ij[p,r]*y[j_p,c]
// Block of <=64 sorted entries loaded once per wave (coalesced), (p,j) extracted
// via v_readlane. 8 independent y-gathers in flight per inner group.
__global__ __launch_bounds__(256) void k_seg(
    const int2* __restrict__ sorted, const int* __restrict__ start,
    const float* __restrict__ f_ij, const float* __restrict__ G,
    const float* __restrict__ y, float* __restrict__ v, int N)
{
    const int c = threadIdx.x & 63;
    const int w = __builtin_amdgcn_readfirstlane((blockIdx.x << 2) | (threadIdx.x >> 6));
    const int nw = gridDim.x << 2;

    float g[16];
    {
        const float4* gp = (const float4*)(G + c * RDIM);
        float4 g0 = gp[0], g1 = gp[1], g2 = gp[2], g3 = gp[3];
        g[0] = g0.x;  g[1] = g0.y;  g[2] = g0.z;  g[3] = g0.w;
        g[4] = g1.x;  g[5] = g1.y;  g[6] = g1.z;  g[7] = g1.w;
        g[8] = g2.x;  g[9] = g2.y;  g[10] = g2.z; g[11] = g2.w;
        g[12] = g3.x; g[13] = g3.y; g[14] = g3.z; g[15] = g3.w;
    }

    for (int a = w; a < N; a += nw) {
        const int s = start[a], e = start[a + 1];
        float vold = v[(size_t)a * FDIM + c];   // hoist RMW read over the pair loop
        float t[16];
#pragma unroll
        for (int r = 0; r < 16; ++r) t[r] = 0.0f;

        for (int base = s; base < e; base += 64) {
            const int nn = (e - base < 64) ? (e - base) : 64;
            const int li = (c < nn) ? c : (nn - 1);
            const int2 E = sorted[base + li];
            const int pk = E.x, jk = E.y;

            int k = 0;
            for (; k + 8 <= nn; k += 8) {
                int pp[8], jj[8];
#pragma unroll
                for (int u = 0; u < 8; ++u) {
                    pp[u] = __builtin_amdgcn_readlane(pk, k + u);
                    jj[u] = __builtin_amdgcn_readlane(jk, k + u);
                }
                float yv[8];
#pragma unroll
                for (int u = 0; u < 8; ++u)
                    yv[u] = y[(size_t)jj[u] * FDIM + c];
#pragma unroll
                for (int u = 0; u < 8; ++u) {
                    const float* f = f_ij + (size_t)pp[u] * RDIM;
#pragma unroll
                    for (int r = 0; r < 16; ++r) t[r] = fmaf(f[r], yv[u], t[r]);
                }
            }
            for (; k + 4 <= nn; k += 4) {
                int pp[4], jj[4];
#pragma unroll
                for (int u = 0; u < 4; ++u) {
                    pp[u] = __builtin_amdgcn_readlane(pk, k + u);
                    jj[u] = __builtin_amdgcn_readlane(jk, k + u);
                }
                float yv[4];
#pragma unroll
                for (int u = 0; u < 4; ++u)
                    yv[u] = y[(size_t)jj[u] * FDIM + c];
#pragma unroll
                for (int u = 0; u < 4; ++u) {
                    const float* f = f_ij + (size_t)pp[u] * RDIM;
#pragma unroll
                    for (int r = 0; r < 16; ++r) t[r] = fmaf(f[r], yv[u], t[r]);
                }
            }
            for (; k < nn; ++k) {
                const int p0 = __builtin_amdgcn_readlane(pk, k);
                const int j0 = __builtin_amdgcn_readlane(jk, k);
                float y0 = y[(size_t)j0 * FDIM + c];
                const float* f0 = f_ij + (size_t)p0 * RDIM;
#pragma unroll
                for (int r = 0; r < 16; ++r) t[r] = fmaf(f0[r], y0, t[r]);
            }
        }

        float acc0 = 0.f, acc1 = 0.f, acc2 = 0.f, acc3 = 0.f;
#pragma unroll
        for (int r = 0; r < 16; r += 4) {
            acc0 = fmaf(g[r + 0], t[r + 0], acc0);
            acc1 = fmaf(g[r + 1], t[r + 1], acc1);
            acc2 = fmaf(g[r + 2], t[r + 2], acc2);
            acc3 = fmaf(g[r + 3], t[r + 3], acc3);
        }
        v[(size_t)a * FDIM + c] = vold + (acc0 + acc1) + (acc2 + acc3);
    }
}

extern "C" void kernel_launch(void* const* d_in, const int* in_sizes, int n_in,
                              void* d_out, int out_size, void* d_ws, size_t ws_size,
                              hipStream_t stream)
{
    const int*   pidx = (const int*)d_in[0];    // [2, P]
    const float* f_ij = (const float*)d_in[1];  // [P, 1, R]
    const float* emb  = (const float*)d_in[3];  // [N, F]
    const float* G    = (const float*)d_in[4];  // [F, R]
    const float* Wi   = (const float*)d_in[5];
    const float* bi   = (const float*)d_in[6];
    const float* Wj   = (const float*)d_in[7];
    const float* bj   = (const float*)d_in[8];
    const float* rW1  = (const float*)d_in[9];
    const float* rb1  = (const float*)d_in[10];
    const float* rW2  = (const float*)d_in[11];
    const float* rb2  = (const float*)d_in[12];
    const float* Wv   = (const float*)d_in[13];
    const float* bv   = (const float*)d_in[14];

    const int P = in_sizes[0] / 2;
    const int N = in_sizes[3] / FDIM;

    float* v = (float*)d_out;

    // workspace layout. Cmat (int[NCHUNK*N]) aliases y (float[N*64]) exactly:
    // the sort pipeline completes before k_atoms writes y.
    char* ws = (char*)d_ws;
    size_t off = 0;
    float*  y      = (float*)(ws + off);
    int*    Cmat   = (int*)(ws + off);    off += (size_t)N * FDIM * 4;
    int*    tot    = (int*)(ws + off);    off += (size_t)N * 4;
    int*    start  = (int*)(ws + off);    off += (size_t)(N + 1) * 4;
    off = (off + 15) & ~(size_t)15;
    int*    part   = (int*)(ws + off);    off += (size_t)4096 * 4;
    off = (off + 15) & ~(size_t)15;
    int2*   sorted = (int2*)(ws + off);   off += (size_t)P * 8;
    off = (off + 15) & ~(size_t)15;
    __bf16* wf     = (__bf16*)(ws + off); off += (size_t)9 * 4096 * 2;
    // wf matrices: 0=Wi 1=Wj 2=W1_0 3=W2_0 4=W1_1 5=W2_1 6=W1_2 7=W2_2 8=Wv

    const int nRange = (N + NBINR - 1) / NBINR;
    const int nPart = (N + 1023) / 1024;
    const int nTiles = (N + 63) >> 6;
    const int gTiles = (nTiles + 3) / 4;   // 1 tile per wave

    dim3 blk(256);
    k_prep<<<9, blk, 0, stream>>>(Wi, Wj, rW1, rW2, rW1 + 4096, rW2 + 4096,
                                  rW1 + 8192, rW2 + 8192, Wv, wf);
    k_hist2<<<NCHUNK * nRange, blk, 0, stream>>>(pidx, Cmat, P, N, nRange);
    k_scanR<<<(N + 511) / 512, blk, 0, stream>>>(Cmat, tot, N);
    k_scan_a<<<nPart, blk, 0, stream>>>(tot, part, N);
    k_scan_b<<<1, blk, 0, stream>>>(part, nPart);
    k_scan_c<<<nPart, blk, 0, stream>>>(tot, part, start, N, P);
    k_scatter2<<<NCHUNK * nRange, blk, 0, stream>>>(pidx, Cmat, start, sorted, P, N, nRange);
    k_atoms<<<gTiles, blk, 0, stream>>>(emb, wf, bi, bj, v, y, N);
    k_seg<<<4096, blk, 0, stream>>>(sorted, start, f_ij, G, y, v, N);
    k_post<<<gTiles, blk, 0, stream>>>(wf + (size_t)2 * 4096, rb1, rb2, bv, v, N);
}